// Round 7
// baseline (302.134 us; speedup 1.0000x reference)
//
#include <hip/hip_runtime.h>
#include <hip/hip_bf16.h>
#include <math.h>

// Problem constants: T=2048, B=2, E=1024, H=16, d=64
constexpr int T_DIM = 2048;
constexpr int B_DIM = 2;
constexpr int E_DIM = 1024;
// Q pre-scale folded into in_proj epilogue: d^-0.5 * log2(e); attention then
// computes p = exp2(s_scaled) = exp(s_orig * d^-0.5).
constexpr float QK_SCALE = 0.18033688011112042f;

#if __has_builtin(__builtin_amdgcn_exp2f)
#define EXP2F(x) __builtin_amdgcn_exp2f(x)
#else
#define EXP2F(x) exp2f(x)
#endif

typedef __attribute__((ext_vector_type(8))) short short8;   // 8 x bf16 (4 VGPRs)
typedef __attribute__((ext_vector_type(4))) float f32x4;    // MFMA C/D frag

__device__ inline short f2bf(float x) {
    union { __hip_bfloat16 b; short s; } u;
    u.b = __float2bfloat16(x);
    return u.s;
}
__device__ inline float bf2f(short s) {
    union { __hip_bfloat16 b; short s; } u;
    u.s = s;
    return __bfloat162float(u.b);
}

// pack two positive f32 to bf16 pair (lo in low half), RNE-ties-away.
__device__ inline int pack_bf16(float hi, float lo) {
    union { float f; unsigned u; } a, b;
    a.f = hi; b.f = lo;
    return (int)__builtin_amdgcn_perm(a.u + 0x8000u, b.u + 0x8000u, 0x07060302u);
}

__device__ inline void gl2lds16(const void* g, void* l) {
    __builtin_amdgcn_global_load_lds(
        (const __attribute__((address_space(1))) unsigned int*)g,
        (__attribute__((address_space(3))) unsigned int*)l, 16, 0, 0);
}

__device__ inline f32x4 mfma_bf16(short8 a, short8 b, f32x4 c) {
    return __builtin_amdgcn_mfma_f32_16x16x32_bf16(a, b, c, 0, 0, 0);
}

// ---------------------------------------------------------------------------
// Fused split: query (hi only), w_in (hi+lo), w_out (hi+lo). One launch.
// ---------------------------------------------------------------------------
__global__ __launch_bounds__(256)
void split_all_kernel(const float* __restrict__ query,
                      const float* __restrict__ w_in,
                      const float* __restrict__ w_out,
                      short* __restrict__ qh,
                      short* __restrict__ wih, short* __restrict__ wil,
                      short* __restrict__ woh, short* __restrict__ wol,
                      int nq4, int nwi4, int nwo4)
{
    int i = blockIdx.x * 256 + threadIdx.x;
    const float* src; short* dh; short* dl; int k; int do_lo;
    if (i < nq4) { src = query; dh = qh; dl = nullptr; k = i; do_lo = 0; }
    else if (i < nq4 + nwi4) { src = w_in; dh = wih; dl = wil; k = i - nq4; do_lo = 1; }
    else { src = w_out; dh = woh; dl = wol; k = i - nq4 - nwi4; do_lo = 1; }
    float4 v = ((const float4*)src)[k];
    short h0 = f2bf(v.x), h1 = f2bf(v.y), h2 = f2bf(v.z), h3 = f2bf(v.w);
    ((short4*)dh)[k] = make_short4(h0, h1, h2, h3);
    if (do_lo) {
        short l0 = f2bf(v.x - bf2f(h0));
        short l1 = f2bf(v.y - bf2f(h1));
        short l2 = f2bf(v.z - bf2f(h2));
        short l3 = f2bf(v.w - bf2f(h3));
        ((short4*)dl)[k] = make_short4(l0, l1, l2, l3);
    }
}

// ---------------------------------------------------------------------------
// 128x128-tile GEMM (in_proj): C = A @ W^T + bias, 2-MFMA w-split, bf16 out,
// q-columns pre-scaled by QK_SCALE.  (core verified r2-r6)
// ---------------------------------------------------------------------------
__global__ __launch_bounds__(256)
void gemm_in(const short* __restrict__ Ah,
             const short* __restrict__ Wh, const short* __restrict__ Wl,
             const float* __restrict__ bias, short* __restrict__ Cout,
             int M, int N, int K)
{
    __shared__ __align__(16) short AsH[128 * 32];
    __shared__ __align__(16) short WsH[128 * 32];
    __shared__ __align__(16) short WsL[128 * 32];

    const int tid  = threadIdx.x;
    const int lane = tid & 63;
    const int wave = tid >> 6;
    const int rm = (wave >> 1) * 64;
    const int cn = (wave & 1) * 64;
    const int m0 = blockIdx.y * 128;
    const int n0 = blockIdx.x * 128;

    const int srow0 = wave * 32 + (lane >> 2);
    const int srow1 = srow0 + 16;
    const int p4 = lane & 3;
    const int kc0 = p4 ^ ((srow0 >> 1) & 3);
    const int kc1 = p4 ^ ((srow1 >> 1) & 3);

    short* ldsA0 = &AsH[(wave * 32) * 32];
    short* ldsA1 = &AsH[(wave * 32 + 16) * 32];
    short* ldsW0 = &WsH[(wave * 32) * 32];
    short* ldsW1 = &WsH[(wave * 32 + 16) * 32];
    short* ldsWl0 = &WsL[(wave * 32) * 32];
    short* ldsWl1 = &WsL[(wave * 32 + 16) * 32];

    const size_t ga0 = (size_t)(m0 + srow0) * K + kc0 * 8;
    const size_t ga1 = (size_t)(m0 + srow1) * K + kc1 * 8;
    const size_t gw0 = (size_t)(n0 + srow0) * K + kc0 * 8;
    const size_t gw1 = (size_t)(n0 + srow1) * K + kc1 * 8;

    const f32x4 zero = {0.f, 0.f, 0.f, 0.f};
    f32x4 acc[4][4];
    #pragma unroll
    for (int i = 0; i < 4; ++i)
        #pragma unroll
        for (int j = 0; j < 4; ++j) acc[i][j] = zero;

    const int fr = lane & 15;
    const int qc = lane >> 4;

    for (int k0 = 0; k0 < K; k0 += 32) {
        if (k0) __syncthreads();
        gl2lds16(Ah + ga0 + k0, ldsA0);
        gl2lds16(Ah + ga1 + k0, ldsA1);
        gl2lds16(Wh + gw0 + k0, ldsW0);
        gl2lds16(Wh + gw1 + k0, ldsW1);
        gl2lds16(Wl + gw0 + k0, ldsWl0);
        gl2lds16(Wl + gw1 + k0, ldsWl1);
        __syncthreads();

        short8 ahf[4], bhf[4], blf[4];
        #pragma unroll
        for (int i = 0; i < 4; ++i) {
            int r = rm + 16 * i + fr;
            int slot = qc ^ ((r >> 1) & 3);
            ahf[i] = *(const short8*)&AsH[r * 32 + slot * 8];
        }
        #pragma unroll
        for (int j = 0; j < 4; ++j) {
            int r = cn + 16 * j + fr;
            int slot = qc ^ ((r >> 1) & 3);
            bhf[j] = *(const short8*)&WsH[r * 32 + slot * 8];
            blf[j] = *(const short8*)&WsL[r * 32 + slot * 8];
        }
        #pragma unroll
        for (int i = 0; i < 4; ++i)
            #pragma unroll
            for (int j = 0; j < 4; ++j) {
                acc[i][j] = mfma_bf16(ahf[i], bhf[j], acc[i][j]);
                acc[i][j] = mfma_bf16(ahf[i], blf[j], acc[i][j]);
            }
    }

    const int g = lane >> 4;
    #pragma unroll
    for (int j = 0; j < 4; ++j) {
        int col = n0 + cn + 16 * j + fr;
        float bj = bias[col];
        float cs = (((col >> 6) % 3) == 0) ? QK_SCALE : 1.0f;
        #pragma unroll
        for (int i = 0; i < 4; ++i)
            #pragma unroll
            for (int r = 0; r < 4; ++r) {
                int row = m0 + rm + 16 * i + g * 4 + r;
                Cout[(size_t)row * N + col] = f2bf((acc[i][j][r] + bj) * cs);
            }
    }
}

// ---------------------------------------------------------------------------
// 64x128-tile GEMM (out_proj): C = A @ W^T + bias, 3-MFMA full split,
// fp32 out. 512 blocks -> 2 blocks/CU (vs 1 at 128x128). Same per-element
// FP accumulation order as the 128-tile kernel (bitwise-identical output).
// Wave w covers M 0..63 x N [w*32, w*32+32).
// ---------------------------------------------------------------------------
__global__ __launch_bounds__(256)
void gemm_out(const short* __restrict__ Ah, const short* __restrict__ Al,
              const short* __restrict__ Wh, const short* __restrict__ Wl,
              const float* __restrict__ bias, float* __restrict__ Cout,
              int M, int N, int K)
{
    __shared__ __align__(16) short AsH[64 * 32];
    __shared__ __align__(16) short AsL[64 * 32];
    __shared__ __align__(16) short WsH[128 * 32];
    __shared__ __align__(16) short WsL[128 * 32];

    const int tid  = threadIdx.x;
    const int lane = tid & 63;
    const int wave = tid >> 6;
    const int m0 = blockIdx.y * 64;
    const int n0 = blockIdx.x * 128;

    // A staging: one issue per plane; wave stages rows wave*16..+15.
    const int arow = wave * 16 + (lane >> 2);
    const int akc = (lane & 3) ^ ((arow >> 1) & 3);
    const size_t gaA = (size_t)(m0 + arow) * K + akc * 8;
    // W staging: two issues per plane; rows wave*32 + i*16 + (lane>>2).
    const int wrow0 = wave * 32 + (lane >> 2);
    const int wrow1 = wrow0 + 16;
    const int wkc0 = (lane & 3) ^ ((wrow0 >> 1) & 3);
    const int wkc1 = (lane & 3) ^ ((wrow1 >> 1) & 3);
    const size_t gw0 = (size_t)(n0 + wrow0) * K + wkc0 * 8;
    const size_t gw1 = (size_t)(n0 + wrow1) * K + wkc1 * 8;

    short* ldsAh = &AsH[wave * 512];
    short* ldsAl = &AsL[wave * 512];
    short* ldsW0 = &WsH[(wave * 2) * 512];
    short* ldsW1 = &WsH[(wave * 2 + 1) * 512];
    short* ldsWl0 = &WsL[(wave * 2) * 512];
    short* ldsWl1 = &WsL[(wave * 2 + 1) * 512];

    const f32x4 zero = {0.f, 0.f, 0.f, 0.f};
    f32x4 acc[4][2];
    #pragma unroll
    for (int i = 0; i < 4; ++i) { acc[i][0] = zero; acc[i][1] = zero; }

    const int fr = lane & 15;
    const int g = lane >> 4;

    for (int k0 = 0; k0 < K; k0 += 32) {
        if (k0) __syncthreads();
        gl2lds16(Ah + gaA + k0, ldsAh);
        gl2lds16(Al + gaA + k0, ldsAl);
        gl2lds16(Wh + gw0 + k0, ldsW0);
        gl2lds16(Wh + gw1 + k0, ldsW1);
        gl2lds16(Wl + gw0 + k0, ldsWl0);
        gl2lds16(Wl + gw1 + k0, ldsWl1);
        __syncthreads();

        short8 ahf[4], alf[4], bhf[2], blf[2];
        #pragma unroll
        for (int i = 0; i < 4; ++i) {
            int r = 16 * i + fr;
            int slot = g ^ ((r >> 1) & 3);
            ahf[i] = *(const short8*)&AsH[r * 32 + slot * 8];
            alf[i] = *(const short8*)&AsL[r * 32 + slot * 8];
        }
        #pragma unroll
        for (int j = 0; j < 2; ++j) {
            int r = wave * 32 + 16 * j + fr;
            int slot = g ^ ((r >> 1) & 3);
            bhf[j] = *(const short8*)&WsH[r * 32 + slot * 8];
            blf[j] = *(const short8*)&WsL[r * 32 + slot * 8];
        }
        #pragma unroll
        for (int i = 0; i < 4; ++i)
            #pragma unroll
            for (int j = 0; j < 2; ++j) {
                acc[i][j] = mfma_bf16(ahf[i], bhf[j], acc[i][j]);
                acc[i][j] = mfma_bf16(ahf[i], blf[j], acc[i][j]);
                acc[i][j] = mfma_bf16(alf[i], bhf[j], acc[i][j]);
            }
    }

    #pragma unroll
    for (int j = 0; j < 2; ++j) {
        int col = n0 + wave * 32 + 16 * j + fr;
        float bj = bias[col];
        #pragma unroll
        for (int i = 0; i < 4; ++i)
            #pragma unroll
            for (int r = 0; r < 4; ++r) {
                int row = m0 + 16 * i + g * 4 + r;
                Cout[(size_t)row * N + col] = acc[i][j][r] + bj;
            }
    }
}

// ---------------------------------------------------------------------------
// One-shot V transpose: qkv [t][b][h*192+128+dd]  ->  vtp [bh][dd][t].
// (verified r5/r6)
// ---------------------------------------------------------------------------
__global__ __launch_bounds__(256)
void repack_vt(const short* __restrict__ qkv, short* __restrict__ vtp)
{
    __shared__ __align__(16) short Vl[64 * 72];

    const int tid = threadIdx.x;
    const int t0 = blockIdx.x * 64;
    const int bh = blockIdx.y;
    const int b = bh >> 4, h = bh & 15;
    const int wv = tid >> 6;
    const int m  = tid & 63;

    const short* src = qkv + ((size_t)(t0 + m) * 2 + b) * 3072 + h * 192 + 128;
    short8 v0 = *(const short8*)(src + (2 * wv) * 8);
    short8 v1 = *(const short8*)(src + (2 * wv + 1) * 8);
    #pragma unroll
    for (int j = 0; j < 8; ++j) {
        Vl[(wv * 16 + j) * 72 + m]     = v0[j];
        Vl[(wv * 16 + 8 + j) * 72 + m] = v1[j];
    }
    __syncthreads();

    const int dd = tid >> 2;
    const int oc = tid & 3;
    uint4 w0 = *(const uint4*)&Vl[dd * 72 + oc * 16];
    uint4 w1 = *(const uint4*)&Vl[dd * 72 + oc * 16 + 8];
    short* dst = vtp + (size_t)bh * (64 * 2048) + (size_t)dd * 2048 + t0 + oc * 16;
    *(uint4*)(dst) = w0;
    *(uint4*)(dst + 8) = w1;
}

// ---------------------------------------------------------------------------
// Flash attention v7: r6's lean per-wave path at 16 waves/CU.
//  * 1024 blocks x 256 threads (4 waves x 16 q-rows): 4 blocks/CU,
//    16 waves/CU — double r6's TLP (the binding constraint, r3-r6 evidence).
//  * register P via S^T + key permutation folded into K-DMA address;
//    V direct from L2-resident vtp; exp2-only softmax; perm-packed bf16.
// ---------------------------------------------------------------------------
__global__ __launch_bounds__(256)
void attn_mfma(const short* __restrict__ qkv, const short* __restrict__ vtp,
               short* __restrict__ ctxh, short* __restrict__ ctxl)
{
    __shared__ __align__(16) short Ks[2][64 * 64];
    __shared__ float Ls[4][16];

    const int tid  = threadIdx.x;
    const int lane = tid & 63;
    const int wave = tid >> 6;
    const int fr = lane & 15;
    const int g  = lane >> 4;

    // XCD-aware decode: 8 groups x 4 bh x 32 q-tiles(64 rows)
    const int id   = blockIdx.x;
    const int slot = id >> 3;
    const int bh   = (id & 7) * 4 + (slot & 3);
    const int q0   = (slot >> 2) * 64;
    const int b = bh >> 4, h = bh & 15;

    // ---- K DMA offsets (permutation + chunk swizzle in global address) ----
    const int chunk = (lane & 7) ^ ((lane >> 3) & 7);
    int koff[2];
    #pragma unroll
    for (int i = 0; i < 2; ++i) {
        int row = wave * 16 + i * 8 + (lane >> 3);
        int kk = (row & 32) | ((row & 12) << 1) | ((row & 16) >> 2) | (row & 3);
        koff[i] = (kk * 2 + b) * 3072 + h * 192 + 64 + chunk * 8;
    }

    // ---- Q fragments (pre-scaled by QK_SCALE in in_proj) ----
    const short* qrow = qkv + ((size_t)(q0 + wave * 16 + fr) * 2 + b) * 3072 + h * 192;
    const short8 aq0 = *(const short8*)(qrow + g * 8);
    const short8 aq1 = *(const short8*)(qrow + 32 + g * 8);

    // ---- V per-lane offsets ----
    const short* vbase = vtp + (size_t)bh * (64 * 2048);
    int voff[4];
    #pragma unroll
    for (int jd = 0; jd < 4; ++jd) voff[jd] = (16 * jd + fr) * 2048 + g * 8;

    const f32x4 zero = {0.f, 0.f, 0.f, 0.f};
    f32x4 o[4];
    #pragma unroll
    for (int jd = 0; jd < 4; ++jd) o[jd] = zero;
    float lsum = 0.f;

    // ---- pre-loop: DMA K tile 0 into buf 0 ----
    #pragma unroll
    for (int i = 0; i < 2; ++i)
        gl2lds16(qkv + koff[i], &Ks[0][(wave * 2 + i) * 512]);

    const int slot0 = (g ^ (fr & 7)) * 8;
    const int slot1 = (((g + 4) ^ (fr & 7)) & 7) * 8;

    for (int s0 = 0; s0 < T_DIM; s0 += 64) {
        const int p = (s0 >> 6) & 1;
        __syncthreads();   // buf p DMA complete; prev reads done

        // V frags for THIS tile (consumed after S-phase: latency covered)
        short8 bv0[4], bv1[4];
        #pragma unroll
        for (int jd = 0; jd < 4; ++jd) {
            const short* vr = vbase + voff[jd] + s0;
            bv0[jd] = *(const short8*)vr;
            bv1[jd] = *(const short8*)(vr + 32);
        }
        // DMA NEXT K tile into buf p^1
        if (s0 + 64 < T_DIM) {
            const short* kb = qkv + (size_t)(s0 + 64) * 6144;
            #pragma unroll
            for (int i = 0; i < 2; ++i)
                gl2lds16(kb + koff[i], &Ks[p ^ 1][(wave * 2 + i) * 512]);
        }

        // ---- S^T = K Q^T, exp2, perm-pack -> register A-frags ----
        int afw[2][4];
        #pragma unroll
        for (int s = 0; s < 4; ++s) {
            const short* kr = &Ks[p][(16 * s + fr) * 64];
            short8 bk0 = *(const short8*)(kr + slot0);
            short8 bk1 = *(const short8*)(kr + slot1);
            f32x4 a = zero;
            a = mfma_bf16(bk0, aq0, a);
            a = mfma_bf16(bk1, aq1, a);
            float e0 = EXP2F(a[0]), e1 = EXP2F(a[1]);
            float e2 = EXP2F(a[2]), e3 = EXP2F(a[3]);
            lsum += (e0 + e1) + (e2 + e3);
            afw[s >> 1][(s & 1) * 2]     = pack_bf16(e1, e0);
            afw[s >> 1][(s & 1) * 2 + 1] = pack_bf16(e3, e2);
        }

        // ---- O += P V (register P, prefetched V) ----
        union { int w[4]; short8 v; } A0, A1;
        #pragma unroll
        for (int w = 0; w < 4; ++w) { A0.w[w] = afw[0][w]; A1.w[w] = afw[1][w]; }
        #pragma unroll
        for (int jd = 0; jd < 4; ++jd) {
            o[jd] = mfma_bf16(A0.v, bv0[jd], o[jd]);
            o[jd] = mfma_bf16(A1.v, bv1[jd], o[jd]);
        }
    }

    // ---- finalize l: combine 4 g-partials per q-column ----
    lsum += __shfl_xor(lsum, 16);
    lsum += __shfl_xor(lsum, 32);
    Ls[wave][fr] = lsum;   // 4 dup writes (g), same value
    __builtin_amdgcn_s_waitcnt(0xc07f);   // lgkmcnt(0): wave-private Ls visible

    // ---- epilogue: normalize, split hi/lo, store ctx ----
    #pragma unroll
    for (int r = 0; r < 4; ++r) {
        float inv = 1.f / Ls[wave][4 * g + r];
        int t = q0 + wave * 16 + 4 * g + r;
        size_t base = ((size_t)t * B_DIM + b) * E_DIM + h * 64;
        #pragma unroll
        for (int jd = 0; jd < 4; ++jd) {
            float v = o[jd][r] * inv;
            short hs = f2bf(v);
            short ls = f2bf(v - bf2f(hs));
            ctxh[base + 16 * jd + fr] = hs;
            ctxl[base + 16 * jd + fr] = ls;
        }
    }
}

// ---------------------------------------------------------------------------
extern "C" void kernel_launch(void* const* d_in, const int* in_sizes, int n_in,
                              void* d_out, int out_size, void* d_ws, size_t ws_size,
                              hipStream_t stream)
{
    const float* query = (const float*)d_in[0];
    const float* w_in  = (const float*)d_in[1];
    const float* b_in  = (const float*)d_in[2];
    const float* w_out = (const float*)d_in[3];
    const float* b_out = (const float*)d_in[4];
    float* out = (float*)d_out;

    char* ws = (char*)d_ws;
    short* qkv  = (short*)(ws);                  // 25.2 MB
    short* qh   = (short*)(ws + 25165824);       // 8.4 MB
    short* wih  = (short*)(ws + 33554432);       // 6.3 MB
    short* wil  = (short*)(ws + 39845888);       // 6.3 MB
    short* woh  = (short*)(ws + 46137344);       // 2.1 MB
    short* wol  = (short*)(ws + 48234496);       // 2.1 MB
    short* vtp  = (short*)(ws + 50331648);       // 8.4 MB  V^T [bh][d][t]
    short* ctxh = (short*)(ws + 25165824);       // alias qh  (dead after in_proj)
    short* ctxl = (short*)(ws + 33554432);       // alias wih (dead after in_proj)

    const int M = T_DIM * B_DIM;  // 4096

    int nq4  = (M * E_DIM) / 4;
    int nwi4 = (3 * E_DIM * E_DIM) / 4;
    int nwo4 = (E_DIM * E_DIM) / 4;
    split_all_kernel<<<(nq4 + nwi4 + nwo4) / 256, 256, 0, stream>>>(
        query, w_in, w_out, qh, wih, wil, woh, wol, nq4, nwi4, nwo4);

    // in_proj: qkv_bf16 = q @ w_in^T + b_in (w-split, 2 MFMA), q-cols pre-scaled
    gemm_in<<<dim3(3 * E_DIM / 128, M / 128), 256, 0, stream>>>(
        qh, wih, wil, b_in, qkv, M, 3 * E_DIM, E_DIM);

    // one-shot V transpose into [bh][d][t]
    repack_vt<<<dim3(T_DIM / 64, 32), 256, 0, stream>>>(qkv, vtp);

    // attention: 1024 blocks x 256 threads, 16 waves/CU
    attn_mfma<<<dim3(1024), 256, 0, stream>>>(qkv, vtp, ctxh, ctxl);

    // out_proj: 64x128 tiles -> 512 blocks (2/CU), full split, 3 MFMA
    gemm_out<<<dim3(E_DIM / 128, M / 64), 256, 0, stream>>>(
        ctxh, ctxl, woh, wol, b_out, out, M, E_DIM, E_DIM);
}

// Round 8
// 266.364 us; speedup vs baseline: 1.1343x; 1.1343x over previous
//
#include <hip/hip_runtime.h>
#include <hip/hip_bf16.h>
#include <math.h>

// Problem constants: T=2048, B=2, E=1024, H=16, d=64
constexpr int T_DIM = 2048;
constexpr int B_DIM = 2;
constexpr int E_DIM = 1024;
// Q pre-scale folded into in_proj epilogue: d^-0.5 * log2(e); attention then
// computes p = exp2(s_scaled) = exp(s_orig * d^-0.5).
constexpr float QK_SCALE = 0.18033688011112042f;

#if __has_builtin(__builtin_amdgcn_exp2f)
#define EXP2F(x) __builtin_amdgcn_exp2f(x)
#else
#define EXP2F(x) exp2f(x)
#endif

typedef __attribute__((ext_vector_type(8))) short short8;   // 8 x bf16 (4 VGPRs)
typedef __attribute__((ext_vector_type(4))) float f32x4;    // MFMA C/D frag

__device__ inline short f2bf(float x) {
    union { __hip_bfloat16 b; short s; } u;
    u.b = __float2bfloat16(x);
    return u.s;
}
__device__ inline float bf2f(short s) {
    union { __hip_bfloat16 b; short s; } u;
    u.s = s;
    return __bfloat162float(u.b);
}

// pack two positive f32 to bf16 pair (lo in low half), RNE-ties-away.
__device__ inline int pack_bf16(float hi, float lo) {
    union { float f; unsigned u; } a, b;
    a.f = hi; b.f = lo;
    return (int)__builtin_amdgcn_perm(a.u + 0x8000u, b.u + 0x8000u, 0x07060302u);
}

__device__ inline void gl2lds16(const void* g, void* l) {
    __builtin_amdgcn_global_load_lds(
        (const __attribute__((address_space(1))) unsigned int*)g,
        (__attribute__((address_space(3))) unsigned int*)l, 16, 0, 0);
}

__device__ inline f32x4 mfma_bf16(short8 a, short8 b, f32x4 c) {
    return __builtin_amdgcn_mfma_f32_16x16x32_bf16(a, b, c, 0, 0, 0);
}

// ---------------------------------------------------------------------------
// Fused split: query (hi only), w_in (hi+lo), w_out (hi+lo). One launch.
// ---------------------------------------------------------------------------
__global__ __launch_bounds__(256)
void split_all_kernel(const float* __restrict__ query,
                      const float* __restrict__ w_in,
                      const float* __restrict__ w_out,
                      short* __restrict__ qh,
                      short* __restrict__ wih, short* __restrict__ wil,
                      short* __restrict__ woh, short* __restrict__ wol,
                      int nq4, int nwi4, int nwo4)
{
    int i = blockIdx.x * 256 + threadIdx.x;
    const float* src; short* dh; short* dl; int k; int do_lo;
    if (i < nq4) { src = query; dh = qh; dl = nullptr; k = i; do_lo = 0; }
    else if (i < nq4 + nwi4) { src = w_in; dh = wih; dl = wil; k = i - nq4; do_lo = 1; }
    else { src = w_out; dh = woh; dl = wol; k = i - nq4 - nwi4; do_lo = 1; }
    float4 v = ((const float4*)src)[k];
    short h0 = f2bf(v.x), h1 = f2bf(v.y), h2 = f2bf(v.z), h3 = f2bf(v.w);
    ((short4*)dh)[k] = make_short4(h0, h1, h2, h3);
    if (do_lo) {
        short l0 = f2bf(v.x - bf2f(h0));
        short l1 = f2bf(v.y - bf2f(h1));
        short l2 = f2bf(v.z - bf2f(h2));
        short l3 = f2bf(v.w - bf2f(h3));
        ((short4*)dl)[k] = make_short4(l0, l1, l2, l3);
    }
}

// ---------------------------------------------------------------------------
// 128x128-tile GEMM (in_proj): C = A @ W^T + bias, 2-MFMA w-split, bf16 out,
// q-columns pre-scaled by QK_SCALE.  (verified r2-r7)
// ---------------------------------------------------------------------------
__global__ __launch_bounds__(256)
void gemm_in(const short* __restrict__ Ah,
             const short* __restrict__ Wh, const short* __restrict__ Wl,
             const float* __restrict__ bias, short* __restrict__ Cout,
             int M, int N, int K)
{
    __shared__ __align__(16) short AsH[128 * 32];
    __shared__ __align__(16) short WsH[128 * 32];
    __shared__ __align__(16) short WsL[128 * 32];

    const int tid  = threadIdx.x;
    const int lane = tid & 63;
    const int wave = tid >> 6;
    const int rm = (wave >> 1) * 64;
    const int cn = (wave & 1) * 64;
    const int m0 = blockIdx.y * 128;
    const int n0 = blockIdx.x * 128;

    const int srow0 = wave * 32 + (lane >> 2);
    const int srow1 = srow0 + 16;
    const int p4 = lane & 3;
    const int kc0 = p4 ^ ((srow0 >> 1) & 3);
    const int kc1 = p4 ^ ((srow1 >> 1) & 3);

    short* ldsA0 = &AsH[(wave * 32) * 32];
    short* ldsA1 = &AsH[(wave * 32 + 16) * 32];
    short* ldsW0 = &WsH[(wave * 32) * 32];
    short* ldsW1 = &WsH[(wave * 32 + 16) * 32];
    short* ldsWl0 = &WsL[(wave * 32) * 32];
    short* ldsWl1 = &WsL[(wave * 32 + 16) * 32];

    const size_t ga0 = (size_t)(m0 + srow0) * K + kc0 * 8;
    const size_t ga1 = (size_t)(m0 + srow1) * K + kc1 * 8;
    const size_t gw0 = (size_t)(n0 + srow0) * K + kc0 * 8;
    const size_t gw1 = (size_t)(n0 + srow1) * K + kc1 * 8;

    const f32x4 zero = {0.f, 0.f, 0.f, 0.f};
    f32x4 acc[4][4];
    #pragma unroll
    for (int i = 0; i < 4; ++i)
        #pragma unroll
        for (int j = 0; j < 4; ++j) acc[i][j] = zero;

    const int fr = lane & 15;
    const int qc = lane >> 4;

    for (int k0 = 0; k0 < K; k0 += 32) {
        if (k0) __syncthreads();
        gl2lds16(Ah + ga0 + k0, ldsA0);
        gl2lds16(Ah + ga1 + k0, ldsA1);
        gl2lds16(Wh + gw0 + k0, ldsW0);
        gl2lds16(Wh + gw1 + k0, ldsW1);
        gl2lds16(Wl + gw0 + k0, ldsWl0);
        gl2lds16(Wl + gw1 + k0, ldsWl1);
        __syncthreads();

        short8 ahf[4], bhf[4], blf[4];
        #pragma unroll
        for (int i = 0; i < 4; ++i) {
            int r = rm + 16 * i + fr;
            int slot = qc ^ ((r >> 1) & 3);
            ahf[i] = *(const short8*)&AsH[r * 32 + slot * 8];
        }
        #pragma unroll
        for (int j = 0; j < 4; ++j) {
            int r = cn + 16 * j + fr;
            int slot = qc ^ ((r >> 1) & 3);
            bhf[j] = *(const short8*)&WsH[r * 32 + slot * 8];
            blf[j] = *(const short8*)&WsL[r * 32 + slot * 8];
        }
        #pragma unroll
        for (int i = 0; i < 4; ++i)
            #pragma unroll
            for (int j = 0; j < 4; ++j) {
                acc[i][j] = mfma_bf16(ahf[i], bhf[j], acc[i][j]);
                acc[i][j] = mfma_bf16(ahf[i], blf[j], acc[i][j]);
            }
    }

    const int g = lane >> 4;
    #pragma unroll
    for (int j = 0; j < 4; ++j) {
        int col = n0 + cn + 16 * j + fr;
        float bj = bias[col];
        float cs = (((col >> 6) % 3) == 0) ? QK_SCALE : 1.0f;
        #pragma unroll
        for (int i = 0; i < 4; ++i)
            #pragma unroll
            for (int r = 0; r < 4; ++r) {
                int row = m0 + rm + 16 * i + g * 4 + r;
                Cout[(size_t)row * N + col] = f2bf((acc[i][j][r] + bj) * cs);
            }
    }
}

// ---------------------------------------------------------------------------
// 64x128-tile GEMM (out_proj): 3-MFMA full split, fp32 out. 512 blocks.
// (verified r7)
// ---------------------------------------------------------------------------
__global__ __launch_bounds__(256)
void gemm_out(const short* __restrict__ Ah, const short* __restrict__ Al,
              const short* __restrict__ Wh, const short* __restrict__ Wl,
              const float* __restrict__ bias, float* __restrict__ Cout,
              int M, int N, int K)
{
    __shared__ __align__(16) short AsH[64 * 32];
    __shared__ __align__(16) short AsL[64 * 32];
    __shared__ __align__(16) short WsH[128 * 32];
    __shared__ __align__(16) short WsL[128 * 32];

    const int tid  = threadIdx.x;
    const int lane = tid & 63;
    const int wave = tid >> 6;
    const int m0 = blockIdx.y * 64;
    const int n0 = blockIdx.x * 128;

    const int arow = wave * 16 + (lane >> 2);
    const int akc = (lane & 3) ^ ((arow >> 1) & 3);
    const size_t gaA = (size_t)(m0 + arow) * K + akc * 8;
    const int wrow0 = wave * 32 + (lane >> 2);
    const int wrow1 = wrow0 + 16;
    const int wkc0 = (lane & 3) ^ ((wrow0 >> 1) & 3);
    const int wkc1 = (lane & 3) ^ ((wrow1 >> 1) & 3);
    const size_t gw0 = (size_t)(n0 + wrow0) * K + wkc0 * 8;
    const size_t gw1 = (size_t)(n0 + wrow1) * K + wkc1 * 8;

    short* ldsAh = &AsH[wave * 512];
    short* ldsAl = &AsL[wave * 512];
    short* ldsW0 = &WsH[(wave * 2) * 512];
    short* ldsW1 = &WsH[(wave * 2 + 1) * 512];
    short* ldsWl0 = &WsL[(wave * 2) * 512];
    short* ldsWl1 = &WsL[(wave * 2 + 1) * 512];

    const f32x4 zero = {0.f, 0.f, 0.f, 0.f};
    f32x4 acc[4][2];
    #pragma unroll
    for (int i = 0; i < 4; ++i) { acc[i][0] = zero; acc[i][1] = zero; }

    const int fr = lane & 15;
    const int g = lane >> 4;

    for (int k0 = 0; k0 < K; k0 += 32) {
        if (k0) __syncthreads();
        gl2lds16(Ah + gaA + k0, ldsAh);
        gl2lds16(Al + gaA + k0, ldsAl);
        gl2lds16(Wh + gw0 + k0, ldsW0);
        gl2lds16(Wh + gw1 + k0, ldsW1);
        gl2lds16(Wl + gw0 + k0, ldsWl0);
        gl2lds16(Wl + gw1 + k0, ldsWl1);
        __syncthreads();

        short8 ahf[4], alf[4], bhf[2], blf[2];
        #pragma unroll
        for (int i = 0; i < 4; ++i) {
            int r = 16 * i + fr;
            int slot = g ^ ((r >> 1) & 3);
            ahf[i] = *(const short8*)&AsH[r * 32 + slot * 8];
            alf[i] = *(const short8*)&AsL[r * 32 + slot * 8];
        }
        #pragma unroll
        for (int j = 0; j < 2; ++j) {
            int r = wave * 32 + 16 * j + fr;
            int slot = g ^ ((r >> 1) & 3);
            bhf[j] = *(const short8*)&WsH[r * 32 + slot * 8];
            blf[j] = *(const short8*)&WsL[r * 32 + slot * 8];
        }
        #pragma unroll
        for (int i = 0; i < 4; ++i)
            #pragma unroll
            for (int j = 0; j < 2; ++j) {
                acc[i][j] = mfma_bf16(ahf[i], bhf[j], acc[i][j]);
                acc[i][j] = mfma_bf16(ahf[i], blf[j], acc[i][j]);
                acc[i][j] = mfma_bf16(alf[i], bhf[j], acc[i][j]);
            }
    }

    #pragma unroll
    for (int j = 0; j < 2; ++j) {
        int col = n0 + wave * 32 + 16 * j + fr;
        float bj = bias[col];
        #pragma unroll
        for (int i = 0; i < 4; ++i)
            #pragma unroll
            for (int r = 0; r < 4; ++r) {
                int row = m0 + 16 * i + g * 4 + r;
                Cout[(size_t)row * N + col] = acc[i][j][r] + bj;
            }
    }
}

// ---------------------------------------------------------------------------
// One-shot V transpose: qkv [t][b][h*192+128+dd] -> vtp [bh][dd][t].
// (verified r5-r7)
// ---------------------------------------------------------------------------
__global__ __launch_bounds__(256)
void repack_vt(const short* __restrict__ qkv, short* __restrict__ vtp)
{
    __shared__ __align__(16) short Vl[64 * 72];

    const int tid = threadIdx.x;
    const int t0 = blockIdx.x * 64;
    const int bh = blockIdx.y;
    const int b = bh >> 4, h = bh & 15;
    const int wv = tid >> 6;
    const int m  = tid & 63;

    const short* src = qkv + ((size_t)(t0 + m) * 2 + b) * 3072 + h * 192 + 128;
    short8 v0 = *(const short8*)(src + (2 * wv) * 8);
    short8 v1 = *(const short8*)(src + (2 * wv + 1) * 8);
    #pragma unroll
    for (int j = 0; j < 8; ++j) {
        Vl[(wv * 16 + j) * 72 + m]     = v0[j];
        Vl[(wv * 16 + 8 + j) * 72 + m] = v1[j];
    }
    __syncthreads();

    const int dd = tid >> 2;
    const int oc = tid & 3;
    uint4 w0 = *(const uint4*)&Vl[dd * 72 + oc * 16];
    uint4 w1 = *(const uint4*)&Vl[dd * 72 + oc * 16 + 8];
    short* dst = vtp + (size_t)bh * (64 * 2048) + (size_t)dd * 2048 + t0 + oc * 16;
    *(uint4*)(dst) = w0;
    *(uint4*)(dst + 8) = w1;
}

// ---------------------------------------------------------------------------
// One-shot K repack into MFMA-fragment order with key permutation baked in:
// kp[bh][tile][frag f = s*2+h][lane l = g*16+fr][j] =
//     K[tile*64 + kk(16s+fr)][h*32 + g*8 + j],
// kk(R) = (R&32)|((R&12)<<1)|((R&16)>>2)|(R&3)   (r6/r7-verified mapping).
// In attention each A-fragment load is then ONE coalesced 1KB b128 burst.
// ---------------------------------------------------------------------------
__global__ __launch_bounds__(256)
void repack_kf(const short* __restrict__ qkv, short* __restrict__ kp)
{
    __shared__ __align__(16) short Kl[64 * 72];

    const int tid = threadIdx.x;
    const int t0 = blockIdx.x * 64;
    const int bh = blockIdx.y;
    const int b = bh >> 4, h = bh & 15;

    // stage-in: 512 chunks of 8 shorts, coalesced per row
    #pragma unroll
    for (int rr = 0; rr < 2; ++rr) {
        int c = tid + 256 * rr;
        int m = c >> 3, c8 = c & 7;
        *(uint4*)&Kl[m * 72 + c8 * 8] =
            *(const uint4*)(qkv + ((size_t)(t0 + m) * 2 + b) * 3072 + h * 192 + 64 + c8 * 8);
    }
    __syncthreads();

    short* dst = kp + (size_t)bh * 131072 + (size_t)blockIdx.x * 4096;
    #pragma unroll
    for (int rr = 0; rr < 2; ++rr) {
        int c = tid + 256 * rr;          // output chunk index 0..511
        int f = c >> 6;                  // frag: s*2+h
        int l = c & 63;                  // lane within frag
        int s = f >> 1, hh = f & 1;
        int g = l >> 4, fr = l & 15;
        int R = 16 * s + fr;
        int kk = (R & 32) | ((R & 12) << 1) | ((R & 16) >> 2) | (R & 3);
        uint4 v = *(const uint4*)&Kl[kk * 72 + hh * 32 + g * 8];
        *(uint4*)(dst + c * 8) = v;      // fully coalesced sequential store
    }
}

// ---------------------------------------------------------------------------
// Flash attention v8 — ZERO LDS, ZERO barriers. Each wave fully independent.
//  * 1024 blocks x 128 threads (2 waves x 32 q-rows).
//  * K A-frags stream from kp (frag-order, sequential 1KB b128 bursts, L2).
//  * V B-frags stream from vtp (L2).  No __syncthreads anywhere -> compiler
//    pipelines loads across the whole loop with fine-grained vmcnt.
//  * register P via S^T C-layout == PV A-layout (key-permutation, verified).
//  * l-sum via ones-MFMA in C-layout (no shuffles, no epilogue LDS).
//  * exp2-only softmax (Q pre-scaled), perm-packed bf16.
// ---------------------------------------------------------------------------
__global__ __launch_bounds__(128, 3)
void attn_mfma(const short* __restrict__ qkv, const short* __restrict__ kp,
               const short* __restrict__ vtp,
               short* __restrict__ ctxh, short* __restrict__ ctxl)
{
    const int tid  = threadIdx.x;
    const int lane = tid & 63;
    const int wave = tid >> 6;
    const int fr = lane & 15;
    const int g  = lane >> 4;

    // XCD-aware decode: 8 groups x 4 bh x 32 q-tiles(64 rows)
    const int id   = blockIdx.x;
    const int slot = id >> 3;
    const int bh   = (id & 7) * 4 + (slot & 3);
    const int q0   = (slot >> 2) * 64;
    const int b = bh >> 4, h = bh & 15;

    // ---- Q fragments: 2 sets of 16 rows (pre-scaled by QK_SCALE) ----
    short8 aq[2][2];
    #pragma unroll
    for (int set = 0; set < 2; ++set) {
        const short* qrow = qkv +
            ((size_t)(q0 + wave * 32 + set * 16 + fr) * 2 + b) * 3072 + h * 192;
        aq[set][0] = *(const short8*)(qrow + g * 8);
        aq[set][1] = *(const short8*)(qrow + 32 + g * 8);
    }

    const short* kb = kp + (size_t)bh * 131072 + lane * 8;
    const short* vb = vtp + (size_t)bh * 131072;
    int voff[4];
    #pragma unroll
    for (int jd = 0; jd < 4; ++jd) voff[jd] = (16 * jd + fr) * 2048 + g * 8;

    short8 ONES;
    #pragma unroll
    for (int i = 0; i < 8; ++i) ONES[i] = (short)0x3F80;  // bf16 1.0

    const f32x4 zero = {0.f, 0.f, 0.f, 0.f};
    f32x4 o[2][4];
    #pragma unroll
    for (int set = 0; set < 2; ++set)
        #pragma unroll
        for (int jd = 0; jd < 4; ++jd) o[set][jd] = zero;
    f32x4 lacc[2] = {zero, zero};

    for (int it = 0; it < 32; ++it) {
        // ---- stream K fragments (sequential 1KB bursts) ----
        const short* kf = kb + it * 4096;
        short8 bk[8];
        #pragma unroll
        for (int f = 0; f < 8; ++f) bk[f] = *(const short8*)(kf + f * 512);
        // ---- stream V fragments ----
        short8 bv0[4], bv1[4];
        #pragma unroll
        for (int jd = 0; jd < 4; ++jd) {
            const short* vr = vb + voff[jd] + it * 64;
            bv0[jd] = *(const short8*)vr;
            bv1[jd] = *(const short8*)(vr + 32);
        }

        // ---- S^T = K Q^T, exp2, perm-pack -> register A-frags ----
        int afw[2][2][4];
        #pragma unroll
        for (int s = 0; s < 4; ++s)
            #pragma unroll
            for (int set = 0; set < 2; ++set) {
                f32x4 a = zero;
                a = mfma_bf16(bk[2 * s], aq[set][0], a);
                a = mfma_bf16(bk[2 * s + 1], aq[set][1], a);
                float e0 = EXP2F(a[0]), e1 = EXP2F(a[1]);
                float e2 = EXP2F(a[2]), e3 = EXP2F(a[3]);
                afw[set][s >> 1][(s & 1) * 2]     = pack_bf16(e1, e0);
                afw[set][s >> 1][(s & 1) * 2 + 1] = pack_bf16(e3, e2);
            }

        // ---- O += P V ; l += P @ ones (all register-resident) ----
        #pragma unroll
        for (int set = 0; set < 2; ++set) {
            union { int w[4]; short8 v; } A0, A1;
            #pragma unroll
            for (int w = 0; w < 4; ++w) { A0.w[w] = afw[set][0][w]; A1.w[w] = afw[set][1][w]; }
            lacc[set] = mfma_bf16(A0.v, ONES, lacc[set]);
            lacc[set] = mfma_bf16(A1.v, ONES, lacc[set]);
            #pragma unroll
            for (int jd = 0; jd < 4; ++jd) {
                o[set][jd] = mfma_bf16(A0.v, bv0[jd], o[set][jd]);
                o[set][jd] = mfma_bf16(A1.v, bv1[jd], o[set][jd]);
            }
        }
    }

    // ---- epilogue: normalize (lacc C-layout matches o), split, store ----
    #pragma unroll
    for (int set = 0; set < 2; ++set)
        #pragma unroll
        for (int r = 0; r < 4; ++r) {
            float inv = 1.f / lacc[set][r];
            int t = q0 + wave * 32 + set * 16 + 4 * g + r;
            size_t base = ((size_t)t * B_DIM + b) * E_DIM + h * 64;
            #pragma unroll
            for (int jd = 0; jd < 4; ++jd) {
                float v = o[set][jd][r] * inv;
                short hs = f2bf(v);
                short ls = f2bf(v - bf2f(hs));
                ctxh[base + 16 * jd + fr] = hs;
                ctxl[base + 16 * jd + fr] = ls;
            }
        }
}

// ---------------------------------------------------------------------------
extern "C" void kernel_launch(void* const* d_in, const int* in_sizes, int n_in,
                              void* d_out, int out_size, void* d_ws, size_t ws_size,
                              hipStream_t stream)
{
    const float* query = (const float*)d_in[0];
    const float* w_in  = (const float*)d_in[1];
    const float* b_in  = (const float*)d_in[2];
    const float* w_out = (const float*)d_in[3];
    const float* b_out = (const float*)d_in[4];
    float* out = (float*)d_out;

    char* ws = (char*)d_ws;
    short* qkv  = (short*)(ws);                  // 25.2 MB
    short* qh   = (short*)(ws + 25165824);       // 8.4 MB
    short* wih  = (short*)(ws + 33554432);       // 6.3 MB
    short* wil  = (short*)(ws + 39845888);       // 6.3 MB
    short* woh  = (short*)(ws + 46137344);       // 2.1 MB
    short* wol  = (short*)(ws + 48234496);       // 2.1 MB
    short* vtp  = (short*)(ws + 50331648);       // 8.4 MB  V^T [bh][d][t]
    short* kp   = (short*)(ws + 58720256);       // 8.4 MB  K frag-order
    short* ctxh = (short*)(ws + 25165824);       // alias qh  (dead after in_proj)
    short* ctxl = (short*)(ws + 33554432);       // alias wih (dead after in_proj)

    const int M = T_DIM * B_DIM;  // 4096

    int nq4  = (M * E_DIM) / 4;
    int nwi4 = (3 * E_DIM * E_DIM) / 4;
    int nwo4 = (E_DIM * E_DIM) / 4;
    split_all_kernel<<<(nq4 + nwi4 + nwo4) / 256, 256, 0, stream>>>(
        query, w_in, w_out, qh, wih, wil, woh, wol, nq4, nwi4, nwo4);

    // in_proj: qkv_bf16 = q @ w_in^T + b_in (w-split, 2 MFMA), q-cols pre-scaled
    gemm_in<<<dim3(3 * E_DIM / 128, M / 128), 256, 0, stream>>>(
        qh, wih, wil, b_in, qkv, M, 3 * E_DIM, E_DIM);

    // one-shot repacks: V -> [bh][d][t], K -> fragment order
    repack_vt<<<dim3(T_DIM / 64, 32), 256, 0, stream>>>(qkv, vtp);
    repack_kf<<<dim3(T_DIM / 64, 32), 256, 0, stream>>>(qkv, kp);

    // attention: 1024 blocks x 128 threads, no LDS, no barriers
    attn_mfma<<<dim3(1024), 128, 0, stream>>>(qkv, kp, vtp, ctxh, ctxl);

    // out_proj: 64x128 tiles -> 512 blocks, full split, 3 MFMA
    gemm_out<<<dim3(E_DIM / 128, M / 64), 256, 0, stream>>>(
        ctxh, ctxl, woh, wol, b_out, out, M, E_DIM, E_DIM);
}

// Round 9
// 255.698 us; speedup vs baseline: 1.1816x; 1.0417x over previous
//
#include <hip/hip_runtime.h>
#include <hip/hip_bf16.h>
#include <math.h>

// Problem constants: T=2048, B=2, E=1024, H=16, d=64
constexpr int T_DIM = 2048;
constexpr int B_DIM = 2;
constexpr int E_DIM = 1024;
// Q pre-scale folded into in_proj epilogue: d^-0.5 * log2(e); attention then
// computes p = exp2(s_scaled) = exp(s_orig * d^-0.5).
constexpr float QK_SCALE = 0.18033688011112042f;

#if __has_builtin(__builtin_amdgcn_exp2f)
#define EXP2F(x) __builtin_amdgcn_exp2f(x)
#else
#define EXP2F(x) exp2f(x)
#endif

typedef __attribute__((ext_vector_type(8))) short short8;   // 8 x bf16 (4 VGPRs)
typedef __attribute__((ext_vector_type(4))) float f32x4;    // MFMA C/D frag

__device__ inline short f2bf(float x) {
    union { __hip_bfloat16 b; short s; } u;
    u.b = __float2bfloat16(x);
    return u.s;
}
__device__ inline float bf2f(short s) {
    union { __hip_bfloat16 b; short s; } u;
    u.s = s;
    return __bfloat162float(u.b);
}

// pack two positive f32 to bf16 pair (lo in low half), RNE-ties-away.
__device__ inline int pack_bf16(float hi, float lo) {
    union { float f; unsigned u; } a, b;
    a.f = hi; b.f = lo;
    return (int)__builtin_amdgcn_perm(a.u + 0x8000u, b.u + 0x8000u, 0x07060302u);
}

__device__ inline void gl2lds16(const void* g, void* l) {
    __builtin_amdgcn_global_load_lds(
        (const __attribute__((address_space(1))) unsigned int*)g,
        (__attribute__((address_space(3))) unsigned int*)l, 16, 0, 0);
}

__device__ inline f32x4 mfma_bf16(short8 a, short8 b, f32x4 c) {
    return __builtin_amdgcn_mfma_f32_16x16x32_bf16(a, b, c, 0, 0, 0);
}

// ---------------------------------------------------------------------------
// Fused split: query (hi only), w_in (hi+lo), w_out (hi+lo). One launch.
// ---------------------------------------------------------------------------
__global__ __launch_bounds__(256)
void split_all_kernel(const float* __restrict__ query,
                      const float* __restrict__ w_in,
                      const float* __restrict__ w_out,
                      short* __restrict__ qh,
                      short* __restrict__ wih, short* __restrict__ wil,
                      short* __restrict__ woh, short* __restrict__ wol,
                      int nq4, int nwi4, int nwo4)
{
    int i = blockIdx.x * 256 + threadIdx.x;
    const float* src; short* dh; short* dl; int k; int do_lo;
    if (i < nq4) { src = query; dh = qh; dl = nullptr; k = i; do_lo = 0; }
    else if (i < nq4 + nwi4) { src = w_in; dh = wih; dl = wil; k = i - nq4; do_lo = 1; }
    else { src = w_out; dh = woh; dl = wol; k = i - nq4 - nwi4; do_lo = 1; }
    float4 v = ((const float4*)src)[k];
    short h0 = f2bf(v.x), h1 = f2bf(v.y), h2 = f2bf(v.z), h3 = f2bf(v.w);
    ((short4*)dh)[k] = make_short4(h0, h1, h2, h3);
    if (do_lo) {
        short l0 = f2bf(v.x - bf2f(h0));
        short l1 = f2bf(v.y - bf2f(h1));
        short l2 = f2bf(v.z - bf2f(h2));
        short l3 = f2bf(v.w - bf2f(h3));
        ((short4*)dl)[k] = make_short4(l0, l1, l2, l3);
    }
}

// ---------------------------------------------------------------------------
// 128x128-tile GEMM (in_proj): C = A @ W^T + bias, 2-MFMA w-split, bf16 out,
// q-columns pre-scaled by QK_SCALE.  (verified r2-r8)
// ---------------------------------------------------------------------------
__global__ __launch_bounds__(256)
void gemm_in(const short* __restrict__ Ah,
             const short* __restrict__ Wh, const short* __restrict__ Wl,
             const float* __restrict__ bias, short* __restrict__ Cout,
             int M, int N, int K)
{
    __shared__ __align__(16) short AsH[128 * 32];
    __shared__ __align__(16) short WsH[128 * 32];
    __shared__ __align__(16) short WsL[128 * 32];

    const int tid  = threadIdx.x;
    const int lane = tid & 63;
    const int wave = tid >> 6;
    const int rm = (wave >> 1) * 64;
    const int cn = (wave & 1) * 64;
    const int m0 = blockIdx.y * 128;
    const int n0 = blockIdx.x * 128;

    const int srow0 = wave * 32 + (lane >> 2);
    const int srow1 = srow0 + 16;
    const int p4 = lane & 3;
    const int kc0 = p4 ^ ((srow0 >> 1) & 3);
    const int kc1 = p4 ^ ((srow1 >> 1) & 3);

    short* ldsA0 = &AsH[(wave * 32) * 32];
    short* ldsA1 = &AsH[(wave * 32 + 16) * 32];
    short* ldsW0 = &WsH[(wave * 32) * 32];
    short* ldsW1 = &WsH[(wave * 32 + 16) * 32];
    short* ldsWl0 = &WsL[(wave * 32) * 32];
    short* ldsWl1 = &WsL[(wave * 32 + 16) * 32];

    const size_t ga0 = (size_t)(m0 + srow0) * K + kc0 * 8;
    const size_t ga1 = (size_t)(m0 + srow1) * K + kc1 * 8;
    const size_t gw0 = (size_t)(n0 + srow0) * K + kc0 * 8;
    const size_t gw1 = (size_t)(n0 + srow1) * K + kc1 * 8;

    const f32x4 zero = {0.f, 0.f, 0.f, 0.f};
    f32x4 acc[4][4];
    #pragma unroll
    for (int i = 0; i < 4; ++i)
        #pragma unroll
        for (int j = 0; j < 4; ++j) acc[i][j] = zero;

    const int fr = lane & 15;
    const int qc = lane >> 4;

    for (int k0 = 0; k0 < K; k0 += 32) {
        if (k0) __syncthreads();
        gl2lds16(Ah + ga0 + k0, ldsA0);
        gl2lds16(Ah + ga1 + k0, ldsA1);
        gl2lds16(Wh + gw0 + k0, ldsW0);
        gl2lds16(Wh + gw1 + k0, ldsW1);
        gl2lds16(Wl + gw0 + k0, ldsWl0);
        gl2lds16(Wl + gw1 + k0, ldsWl1);
        __syncthreads();

        short8 ahf[4], bhf[4], blf[4];
        #pragma unroll
        for (int i = 0; i < 4; ++i) {
            int r = rm + 16 * i + fr;
            int slot = qc ^ ((r >> 1) & 3);
            ahf[i] = *(const short8*)&AsH[r * 32 + slot * 8];
        }
        #pragma unroll
        for (int j = 0; j < 4; ++j) {
            int r = cn + 16 * j + fr;
            int slot = qc ^ ((r >> 1) & 3);
            bhf[j] = *(const short8*)&WsH[r * 32 + slot * 8];
            blf[j] = *(const short8*)&WsL[r * 32 + slot * 8];
        }
        #pragma unroll
        for (int i = 0; i < 4; ++i)
            #pragma unroll
            for (int j = 0; j < 4; ++j) {
                acc[i][j] = mfma_bf16(ahf[i], bhf[j], acc[i][j]);
                acc[i][j] = mfma_bf16(ahf[i], blf[j], acc[i][j]);
            }
    }

    const int g = lane >> 4;
    #pragma unroll
    for (int j = 0; j < 4; ++j) {
        int col = n0 + cn + 16 * j + fr;
        float bj = bias[col];
        float cs = (((col >> 6) % 3) == 0) ? QK_SCALE : 1.0f;
        #pragma unroll
        for (int i = 0; i < 4; ++i)
            #pragma unroll
            for (int r = 0; r < 4; ++r) {
                int row = m0 + rm + 16 * i + g * 4 + r;
                Cout[(size_t)row * N + col] = f2bf((acc[i][j][r] + bj) * cs);
            }
    }
}

// ---------------------------------------------------------------------------
// 64x128-tile GEMM (out_proj): 3-MFMA full split, fp32 out. 512 blocks.
// (verified r7/r8)
// ---------------------------------------------------------------------------
__global__ __launch_bounds__(256)
void gemm_out(const short* __restrict__ Ah, const short* __restrict__ Al,
              const short* __restrict__ Wh, const short* __restrict__ Wl,
              const float* __restrict__ bias, float* __restrict__ Cout,
              int M, int N, int K)
{
    __shared__ __align__(16) short AsH[64 * 32];
    __shared__ __align__(16) short AsL[64 * 32];
    __shared__ __align__(16) short WsH[128 * 32];
    __shared__ __align__(16) short WsL[128 * 32];

    const int tid  = threadIdx.x;
    const int lane = tid & 63;
    const int wave = tid >> 6;
    const int m0 = blockIdx.y * 64;
    const int n0 = blockIdx.x * 128;

    const int arow = wave * 16 + (lane >> 2);
    const int akc = (lane & 3) ^ ((arow >> 1) & 3);
    const size_t gaA = (size_t)(m0 + arow) * K + akc * 8;
    const int wrow0 = wave * 32 + (lane >> 2);
    const int wrow1 = wrow0 + 16;
    const int wkc0 = (lane & 3) ^ ((wrow0 >> 1) & 3);
    const int wkc1 = (lane & 3) ^ ((wrow1 >> 1) & 3);
    const size_t gw0 = (size_t)(n0 + wrow0) * K + wkc0 * 8;
    const size_t gw1 = (size_t)(n0 + wrow1) * K + wkc1 * 8;

    short* ldsAh = &AsH[wave * 512];
    short* ldsAl = &AsL[wave * 512];
    short* ldsW0 = &WsH[(wave * 2) * 512];
    short* ldsW1 = &WsH[(wave * 2 + 1) * 512];
    short* ldsWl0 = &WsL[(wave * 2) * 512];
    short* ldsWl1 = &WsL[(wave * 2 + 1) * 512];

    const f32x4 zero = {0.f, 0.f, 0.f, 0.f};
    f32x4 acc[4][2];
    #pragma unroll
    for (int i = 0; i < 4; ++i) { acc[i][0] = zero; acc[i][1] = zero; }

    const int fr = lane & 15;
    const int g = lane >> 4;

    for (int k0 = 0; k0 < K; k0 += 32) {
        if (k0) __syncthreads();
        gl2lds16(Ah + gaA + k0, ldsAh);
        gl2lds16(Al + gaA + k0, ldsAl);
        gl2lds16(Wh + gw0 + k0, ldsW0);
        gl2lds16(Wh + gw1 + k0, ldsW1);
        gl2lds16(Wl + gw0 + k0, ldsWl0);
        gl2lds16(Wl + gw1 + k0, ldsWl1);
        __syncthreads();

        short8 ahf[4], alf[4], bhf[2], blf[2];
        #pragma unroll
        for (int i = 0; i < 4; ++i) {
            int r = 16 * i + fr;
            int slot = g ^ ((r >> 1) & 3);
            ahf[i] = *(const short8*)&AsH[r * 32 + slot * 8];
            alf[i] = *(const short8*)&AsL[r * 32 + slot * 8];
        }
        #pragma unroll
        for (int j = 0; j < 2; ++j) {
            int r = wave * 32 + 16 * j + fr;
            int slot = g ^ ((r >> 1) & 3);
            bhf[j] = *(const short8*)&WsH[r * 32 + slot * 8];
            blf[j] = *(const short8*)&WsL[r * 32 + slot * 8];
        }
        #pragma unroll
        for (int i = 0; i < 4; ++i)
            #pragma unroll
            for (int j = 0; j < 2; ++j) {
                acc[i][j] = mfma_bf16(ahf[i], bhf[j], acc[i][j]);
                acc[i][j] = mfma_bf16(ahf[i], blf[j], acc[i][j]);
                acc[i][j] = mfma_bf16(alf[i], bhf[j], acc[i][j]);
            }
    }

    #pragma unroll
    for (int j = 0; j < 2; ++j) {
        int col = n0 + wave * 32 + 16 * j + fr;
        float bj = bias[col];
        #pragma unroll
        for (int i = 0; i < 4; ++i)
            #pragma unroll
            for (int r = 0; r < 4; ++r) {
                int row = m0 + 16 * i + g * 4 + r;
                Cout[(size_t)row * N + col] = acc[i][j][r] + bj;
            }
    }
}

// ---------------------------------------------------------------------------
// One-shot V transpose: qkv [t][b][h*192+128+dd] -> vtp [bh][dd][t].
// (verified r5-r8)
// ---------------------------------------------------------------------------
__global__ __launch_bounds__(256)
void repack_vt(const short* __restrict__ qkv, short* __restrict__ vtp)
{
    __shared__ __align__(16) short Vl[64 * 72];

    const int tid = threadIdx.x;
    const int t0 = blockIdx.x * 64;
    const int bh = blockIdx.y;
    const int b = bh >> 4, h = bh & 15;
    const int wv = tid >> 6;
    const int m  = tid & 63;

    const short* src = qkv + ((size_t)(t0 + m) * 2 + b) * 3072 + h * 192 + 128;
    short8 v0 = *(const short8*)(src + (2 * wv) * 8);
    short8 v1 = *(const short8*)(src + (2 * wv + 1) * 8);
    #pragma unroll
    for (int j = 0; j < 8; ++j) {
        Vl[(wv * 16 + j) * 72 + m]     = v0[j];
        Vl[(wv * 16 + 8 + j) * 72 + m] = v1[j];
    }
    __syncthreads();

    const int dd = tid >> 2;
    const int oc = tid & 3;
    uint4 w0 = *(const uint4*)&Vl[dd * 72 + oc * 16];
    uint4 w1 = *(const uint4*)&Vl[dd * 72 + oc * 16 + 8];
    short* dst = vtp + (size_t)bh * (64 * 2048) + (size_t)dd * 2048 + t0 + oc * 16;
    *(uint4*)(dst) = w0;
    *(uint4*)(dst + 8) = w1;
}

// ---------------------------------------------------------------------------
// One-shot K repack into MFMA-fragment order with key permutation baked in.
// (verified r8)
// ---------------------------------------------------------------------------
__global__ __launch_bounds__(256)
void repack_kf(const short* __restrict__ qkv, short* __restrict__ kp)
{
    __shared__ __align__(16) short Kl[64 * 72];

    const int tid = threadIdx.x;
    const int t0 = blockIdx.x * 64;
    const int bh = blockIdx.y;
    const int b = bh >> 4, h = bh & 15;

    #pragma unroll
    for (int rr = 0; rr < 2; ++rr) {
        int c = tid + 256 * rr;
        int m = c >> 3, c8 = c & 7;
        *(uint4*)&Kl[m * 72 + c8 * 8] =
            *(const uint4*)(qkv + ((size_t)(t0 + m) * 2 + b) * 3072 + h * 192 + 64 + c8 * 8);
    }
    __syncthreads();

    short* dst = kp + (size_t)bh * 131072 + (size_t)blockIdx.x * 4096;
    #pragma unroll
    for (int rr = 0; rr < 2; ++rr) {
        int c = tid + 256 * rr;
        int f = c >> 6;
        int l = c & 63;
        int s = f >> 1, hh = f & 1;
        int g = l >> 4, fr = l & 15;
        int R = 16 * s + fr;
        int kk = (R & 32) | ((R & 12) << 1) | ((R & 16) >> 2) | (R & 3);
        uint4 v = *(const uint4*)&Kl[kk * 72 + hh * 32 + g * 8];
        *(uint4*)(dst + c * 8) = v;
    }
}

// ---------------------------------------------------------------------------
// Flash attention v9 — r8 (zero LDS / zero barriers) + explicit register
// double-buffering: loop unrolled x2 with A/B tile buffers so tile i+1's 16
// L2 loads are in flight during tile i's ~600-cycle compute. VGPR budget
// ~220 (launch_bounds(128,2) caps 256; 2 waves/SIMD kept).
// ---------------------------------------------------------------------------
__global__ __launch_bounds__(128, 2)
void attn_mfma(const short* __restrict__ qkv, const short* __restrict__ kp,
               const short* __restrict__ vtp,
               short* __restrict__ ctxh, short* __restrict__ ctxl)
{
    const int tid  = threadIdx.x;
    const int lane = tid & 63;
    const int wave = tid >> 6;
    const int fr = lane & 15;
    const int g  = lane >> 4;

    // XCD-aware decode: 8 groups x 4 bh x 32 q-tiles(64 rows)
    const int id   = blockIdx.x;
    const int slot = id >> 3;
    const int bh   = (id & 7) * 4 + (slot & 3);
    const int q0   = (slot >> 2) * 64;
    const int b = bh >> 4, h = bh & 15;

    // ---- Q fragments: 2 sets of 16 rows (pre-scaled by QK_SCALE) ----
    short8 aq[2][2];
    #pragma unroll
    for (int set = 0; set < 2; ++set) {
        const short* qrow = qkv +
            ((size_t)(q0 + wave * 32 + set * 16 + fr) * 2 + b) * 3072 + h * 192;
        aq[set][0] = *(const short8*)(qrow + g * 8);
        aq[set][1] = *(const short8*)(qrow + 32 + g * 8);
    }

    const short* kb = kp + (size_t)bh * 131072 + lane * 8;
    const short* vb = vtp + (size_t)bh * 131072;
    int voff[4];
    #pragma unroll
    for (int jd = 0; jd < 4; ++jd) voff[jd] = (16 * jd + fr) * 2048 + g * 8;

    short8 ONES;
    #pragma unroll
    for (int i = 0; i < 8; ++i) ONES[i] = (short)0x3F80;  // bf16 1.0

    const f32x4 zero = {0.f, 0.f, 0.f, 0.f};
    f32x4 o[2][4];
    #pragma unroll
    for (int set = 0; set < 2; ++set)
        #pragma unroll
        for (int jd = 0; jd < 4; ++jd) o[set][jd] = zero;
    f32x4 lacc[2] = {zero, zero};

    // load tile `it` into register buffers (16 b128 loads, no waits here)
    auto load_tile = [&](int it, short8* bk, short8* bv) {
        const short* kf = kb + it * 4096;
        #pragma unroll
        for (int f = 0; f < 8; ++f) bk[f] = *(const short8*)(kf + f * 512);
        #pragma unroll
        for (int jd = 0; jd < 4; ++jd) {
            const short* vr = vb + voff[jd] + it * 64;
            bv[2 * jd]     = *(const short8*)vr;
            bv[2 * jd + 1] = *(const short8*)(vr + 32);
        }
    };

    // compute one 64-key tile from register buffers
    auto compute_tile = [&](const short8* bk, const short8* bv) {
        int afw[2][2][4];
        #pragma unroll
        for (int s = 0; s < 4; ++s)
            #pragma unroll
            for (int set = 0; set < 2; ++set) {
                f32x4 a = zero;
                a = mfma_bf16(bk[2 * s], aq[set][0], a);
                a = mfma_bf16(bk[2 * s + 1], aq[set][1], a);
                float e0 = EXP2F(a[0]), e1 = EXP2F(a[1]);
                float e2 = EXP2F(a[2]), e3 = EXP2F(a[3]);
                afw[set][s >> 1][(s & 1) * 2]     = pack_bf16(e1, e0);
                afw[set][s >> 1][(s & 1) * 2 + 1] = pack_bf16(e3, e2);
            }
        #pragma unroll
        for (int set = 0; set < 2; ++set) {
            union { int w[4]; short8 v; } A0, A1;
            #pragma unroll
            for (int w = 0; w < 4; ++w) { A0.w[w] = afw[set][0][w]; A1.w[w] = afw[set][1][w]; }
            lacc[set] = mfma_bf16(A0.v, ONES, lacc[set]);
            lacc[set] = mfma_bf16(A1.v, ONES, lacc[set]);
            #pragma unroll
            for (int jd = 0; jd < 4; ++jd) {
                o[set][jd] = mfma_bf16(A0.v, bv[2 * jd], o[set][jd]);
                o[set][jd] = mfma_bf16(A1.v, bv[2 * jd + 1], o[set][jd]);
            }
        }
    };

    short8 bkA[8], bvA[8], bkB[8], bvB[8];
    load_tile(0, bkA, bvA);
    #pragma unroll 1
    for (int it = 0; it < 32; it += 2) {
        load_tile(it + 1, bkB, bvB);          // in flight during compute A
        compute_tile(bkA, bvA);
        if (it + 2 < 32) load_tile(it + 2, bkA, bvA);  // in flight during B
        compute_tile(bkB, bvB);
    }

    // ---- epilogue: normalize (lacc C-layout matches o), split, store ----
    #pragma unroll
    for (int set = 0; set < 2; ++set)
        #pragma unroll
        for (int r = 0; r < 4; ++r) {
            float inv = 1.f / lacc[set][r];
            int t = q0 + wave * 32 + set * 16 + 4 * g + r;
            size_t base = ((size_t)t * B_DIM + b) * E_DIM + h * 64;
            #pragma unroll
            for (int jd = 0; jd < 4; ++jd) {
                float v = o[set][jd][r] * inv;
                short hs = f2bf(v);
                short ls = f2bf(v - bf2f(hs));
                ctxh[base + 16 * jd + fr] = hs;
                ctxl[base + 16 * jd + fr] = ls;
            }
        }
}

// ---------------------------------------------------------------------------
extern "C" void kernel_launch(void* const* d_in, const int* in_sizes, int n_in,
                              void* d_out, int out_size, void* d_ws, size_t ws_size,
                              hipStream_t stream)
{
    const float* query = (const float*)d_in[0];
    const float* w_in  = (const float*)d_in[1];
    const float* b_in  = (const float*)d_in[2];
    const float* w_out = (const float*)d_in[3];
    const float* b_out = (const float*)d_in[4];
    float* out = (float*)d_out;

    char* ws = (char*)d_ws;
    short* qkv  = (short*)(ws);                  // 25.2 MB
    short* qh   = (short*)(ws + 25165824);       // 8.4 MB
    short* wih  = (short*)(ws + 33554432);       // 6.3 MB
    short* wil  = (short*)(ws + 39845888);       // 6.3 MB
    short* woh  = (short*)(ws + 46137344);       // 2.1 MB
    short* wol  = (short*)(ws + 48234496);       // 2.1 MB
    short* vtp  = (short*)(ws + 50331648);       // 8.4 MB  V^T [bh][d][t]
    short* kp   = (short*)(ws + 58720256);       // 8.4 MB  K frag-order
    short* ctxh = (short*)(ws + 25165824);       // alias qh  (dead after in_proj)
    short* ctxl = (short*)(ws + 33554432);       // alias wih (dead after in_proj)

    const int M = T_DIM * B_DIM;  // 4096

    int nq4  = (M * E_DIM) / 4;
    int nwi4 = (3 * E_DIM * E_DIM) / 4;
    int nwo4 = (E_DIM * E_DIM) / 4;
    split_all_kernel<<<(nq4 + nwi4 + nwo4) / 256, 256, 0, stream>>>(
        query, w_in, w_out, qh, wih, wil, woh, wol, nq4, nwi4, nwo4);

    // in_proj: qkv_bf16 = q @ w_in^T + b_in (w-split, 2 MFMA), q-cols pre-scaled
    gemm_in<<<dim3(3 * E_DIM / 128, M / 128), 256, 0, stream>>>(
        qh, wih, wil, b_in, qkv, M, 3 * E_DIM, E_DIM);

    // one-shot repacks: V -> [bh][d][t], K -> fragment order
    repack_vt<<<dim3(T_DIM / 64, 32), 256, 0, stream>>>(qkv, vtp);
    repack_kf<<<dim3(T_DIM / 64, 32), 256, 0, stream>>>(qkv, kp);

    // attention: 1024 blocks x 128 threads, no LDS/barriers, reg dbuf
    attn_mfma<<<dim3(1024), 128, 0, stream>>>(qkv, kp, vtp, ctxh, ctxl);

    // out_proj: 64x128 tiles -> 512 blocks, full split, 3 MFMA
    gemm_out<<<dim3(E_DIM / 128, M / 64), 256, 0, stream>>>(
        ctxh, ctxl, woh, wol, b_out, out, M, E_DIM, E_DIM);
}